// Round 6
// baseline (112.955 us; speedup 1.0000x reference)
//
#include <hip/hip_runtime.h>

typedef unsigned short ushort_t;
typedef __bf16 bf16x8 __attribute__((ext_vector_type(8)));
typedef float f32x4 __attribute__((ext_vector_type(4)));
typedef void __attribute__((address_space(1))) gvoid_t;
typedef void __attribute__((address_space(3))) lvoid_t;

__device__ __forceinline__ float bflo(unsigned u) { return __builtin_bit_cast(float, u << 16); }
__device__ __forceinline__ float bfhi(unsigned u) { return __builtin_bit_cast(float, u & 0xffff0000u); }
__device__ __forceinline__ unsigned f2bf_bits(float f) {
  unsigned u = __builtin_bit_cast(unsigned, f);
  return (u + 0x7fffu + ((u >> 16) & 1u)) >> 16;
}
__device__ __forceinline__ ushort_t f2bf(float f) { return (ushort_t)f2bf_bits(f); }

#define VMWAIT(N) asm volatile("s_waitcnt vmcnt(" #N ")" ::: "memory")
#define LGKM0 asm volatile("s_waitcnt lgkmcnt(0)" ::: "memory")

// ---------------- prep: weight (o,c,k) f32 -> wb[k][o][c] bf16 ----------------
__global__ __launch_bounds__(256) void k_prep_w(const float* __restrict__ w,
                                                ushort_t* __restrict__ wb) {
  const int idx = blockIdx.x * 256 + threadIdx.x;  // (o,c) pair, 65536 total
  const float* src = w + (size_t)idx * 9;
  #pragma unroll
  for (int k = 0; k < 9; ++k)
    wb[(k << 16) + idx] = f2bf(src[k]);
}

// ---------------- prep: x (b,c,h,w) f32 -> xt[b][h][w][c] bf16 ----------------
__global__ __launch_bounds__(256) void k_prep_x(const float* __restrict__ x,
                                                ushort_t* __restrict__ xt) {
  __shared__ ushort_t tile[64][68];
  const int bid = blockIdx.x;             // 4b * 4ct * 64pt = 1024
  const int b = bid >> 8;
  const int ct = (bid >> 6) & 3;
  const int pt = bid & 63;
  const int t = threadIdx.x;
  const float* xb = x + ((size_t)(b * 256 + ct * 64)) * 4096 + pt * 64;
  #pragma unroll
  for (int i = 0; i < 16; ++i) {
    const int idx = t + 256 * i;
    const int c_l = idx >> 6, p_l = idx & 63;
    tile[c_l][p_l] = f2bf(xb[(size_t)c_l * 4096 + p_l]);
  }
  __syncthreads();
  ushort_t* xo = xt + ((size_t)(b * 4096 + pt * 64)) * 256 + ct * 64;
  #pragma unroll
  for (int i = 0; i < 16; ++i) {
    const int idx = t + 256 * i;
    const int p_l = idx >> 6, c_l = idx & 63;
    xo[(size_t)p_l * 256 + c_l] = tile[c_l][p_l];
  }
}

// bilinear meta for one (h, w, tap) — weights and gather base offsets (in ushorts)
struct SMeta {
  float w00, w01, w10, w11;
  int i00, i01, i10, i11;
};
__device__ __forceinline__ SMeta meta_for(int h, int gw, int k, float oy, float ox) {
  SMeta m;
  const float py = (float)(h - 1 + k / 3) + oy;
  const float px = (float)(gw - 1 + k % 3) + ox;
  const float fy = floorf(py), fx = floorf(px);
  const float ly = py - fy, lx = px - fx;
  const int iy0 = (int)fy, ix0 = (int)fx;
  const float vy0 = (iy0 >= 0 && iy0 < 64) ? 1.f : 0.f;
  const float vy1 = (iy0 >= -1 && iy0 < 63) ? 1.f : 0.f;
  const float vx0 = (ix0 >= 0 && ix0 < 64) ? 1.f : 0.f;
  const float vx1 = (ix0 >= -1 && ix0 < 63) ? 1.f : 0.f;
  m.w00 = (1.f - ly) * (1.f - lx) * vy0 * vx0;
  m.w01 = (1.f - ly) * lx * vy0 * vx1;
  m.w10 = ly * (1.f - lx) * vy1 * vx0;
  m.w11 = ly * lx * vy1 * vx1;
  const int cy0 = min(max(iy0, 0), 63), cy1 = min(max(iy0 + 1, 0), 63);
  const int cx0 = min(max(ix0, 0), 63), cx1 = min(max(ix0 + 1, 0), 63);
  m.i00 = (cy0 * 64 + cx0) * 256;
  m.i01 = (cy0 * 64 + cx1) * 256;
  m.i10 = (cy1 * 64 + cx0) * 256;
  m.i11 = (cy1 * 64 + cx1) * 256;
  return m;
}

__device__ __forceinline__ unsigned lerp_pack(unsigned a, unsigned b, unsigned c, unsigned d,
                                              float w00, float w01, float w10, float w11) {
  float lo = w00 * bflo(a) + w01 * bflo(b) + w10 * bflo(c) + w11 * bflo(d);
  float hi = w00 * bfhi(a) + w01 * bfhi(b) + w10 * bfhi(c) + w11 * bfhi(d);
  return f2bf_bits(lo) | (f2bf_bits(hi) << 16);
}

// ---------------- fused deform-sample + GEMM + GN partial stats ----------------
// block = half output row (b,h,wh): BM=32 (w), BN=256 (o), 8 waves (512 thr).
// grid=512 -> 2 independent blocks/CU (LDS 72KB, VGPR<=128) so one block's
// pack-VALU phase overlaps the other's LDS/MFMA phase.
// Sampling by waves 0-3 (256 thr x 8ch); waves 4-7 only stage B + MFMA.
// Pipeline: A/B double-buffered, prefetch distance 1, raw s_barrier + counted
// vmcnt (per-wave-group counts: sampling waves carry 8 loads, others 4).
// XCD swizzle: lb=(bid&7)*64+bid/8 -> each XCD works one half-batch (L2-resident).
__global__ __launch_bounds__(512) void k_gemm(const float* __restrict__ off,
                                              const ushort_t* __restrict__ xt,
                                              const ushort_t* __restrict__ wb,
                                              float* __restrict__ y,
                                              float* __restrict__ stats) {
  __shared__ __attribute__((aligned(16))) ushort_t Abuf[2][32 * 64];   // 8KB
  __shared__ __attribute__((aligned(16))) ushort_t Bbuf[2][256 * 64];  // 64KB

  const int bid = blockIdx.x;                    // 512
  const int lb = ((bid & 7) << 6) | (bid >> 3);  // XCD-contiguous logical id
  const int b = lb >> 7;
  const int h = (lb >> 1) & 63;
  const int wh = lb & 1;
  const int t = threadIdx.x;  // 0..511
  const int wave = t >> 6;
  const int lane = t & 63;
  const int wq = lane >> 4;
  const int wr = lane & 15;
  const int wm = wave >> 2;  // M half (16 rows each)
  const int wn = wave & 3;   // N quarter
  const bool samp = (t < 256);

  const int s_w = (t >> 3) & 31;  // sampling: local w column (0..31)
  const int c8 = t & 7;           // sampling: 8-channel slice (0..7)
  const int gw = wh * 32 + s_w;   // global w

  const f32x4 zero = {0.f, 0.f, 0.f, 0.f};
  f32x4 acc[4];
  #pragma unroll
  for (int j = 0; j < 4; ++j) acc[j] = zero;

  const ushort_t* xtb = xt + (size_t)b * 4096 * 256;

  // hoist offsets (sampling threads only)
  float oy[9], ox[9];
  if (samp) {
    const float* offb = off + (size_t)b * 18 * 4096 + h * 64 + gw;
    #pragma unroll
    for (int k = 0; k < 9; ++k) {
      oy[k] = offb[(2 * k) * 4096];
      ox[k] = offb[(2 * k + 1) * 4096];
    }
  }

#define GATHER_ISSUE(TAP, C0)                           \
  {                                                     \
    m = meta_for(h, gw, (TAP), oy[(TAP)], ox[(TAP)]);   \
    const int cc = (C0) + c8 * 8;                       \
    q00 = *(const uint4*)(xtb + m.i00 + cc);            \
    q01 = *(const uint4*)(xtb + m.i01 + cc);            \
    q10 = *(const uint4*)(xtb + m.i10 + cc);            \
    q11 = *(const uint4*)(xtb + m.i11 + cc);            \
  }

#define B_ISSUE(TAP, C0, BUF)                                                                \
  {                                                                                          \
    _Pragma("unroll") for (int i_ = 0; i_ < 4; ++i_) {                                       \
      const int idx_ = i_ * 512 + t;                                                         \
      const int row_ = idx_ >> 3, slot_ = idx_ & 7;                                          \
      const ushort_t* g_ = wb + ((TAP) << 16) + row_ * 256 + (C0) + ((slot_ ^ (row_ & 7)) << 3); \
      __builtin_amdgcn_global_load_lds((gvoid_t*)g_,                                         \
                                       (lvoid_t*)((char*)&Bbuf[(BUF)][0] + idx_ * 16), 16,   \
                                       0, 0);                                                \
    }                                                                                        \
  }

#define A_WRITE(BUF)                                                         \
  {                                                                          \
    uint4 r;                                                                 \
    r.x = lerp_pack(q00.x, q01.x, q10.x, q11.x, m.w00, m.w01, m.w10, m.w11); \
    r.y = lerp_pack(q00.y, q01.y, q10.y, q11.y, m.w00, m.w01, m.w10, m.w11); \
    r.z = lerp_pack(q00.z, q01.z, q10.z, q11.z, m.w00, m.w01, m.w10, m.w11); \
    r.w = lerp_pack(q00.w, q01.w, q10.w, q11.w, m.w00, m.w01, m.w10, m.w11); \
    *(uint4*)&Abuf[(BUF)][s_w * 64 + ((c8 ^ (s_w & 7)) << 3)] = r;           \
  }

  // ---- prologue: gathers(0) [samp] + B(0); pack A(0) ----
  {
    uint4 q00, q01, q10, q11;
    SMeta m;
    if (samp) {
      GATHER_ISSUE(0, 0);
    }
    B_ISSUE(0, 0, 0);
    if (samp) {
      VMWAIT(4);  // drain gathers(0); B(0) stays in flight
      A_WRITE(0);
    }
    LGKM0;
    __builtin_amdgcn_s_barrier();
  }

  // ---- main loop: 36 periods, fully unrolled ----
  #pragma unroll
  for (int n = 0; n < 36; ++n) {
    const int cur = n & 1;
    const int nb = cur ^ 1;
    uint4 q00, q01, q10, q11;
    SMeta m;
    if (n < 35) {
      if (samp) {
        GATHER_ISSUE((n + 1) >> 2, ((n + 1) & 3) << 6);
      }
      B_ISSUE((n + 1) >> 2, ((n + 1) & 3) << 6, nb);
      // retire B(n) before reading it (outstanding: samp [B(n),g(n+1),B(n+1)]=12,
      // else [B(n),B(n+1)]=8)
      if (samp) {
        VMWAIT(8);
      } else {
        VMWAIT(4);
      }
    } else {
      VMWAIT(0);  // last period: only B(35) outstanding
    }
    // compute chunk n from buf[cur]
    #pragma unroll
    for (int ks = 0; ks < 2; ++ks) {
      bf16x8 af, bfr[4];
      {
        const int row = wm * 16 + wr;
        const int slot = (ks * 4 + wq) ^ (row & 7);
        af = *(const bf16x8*)&Abuf[cur][row * 64 + slot * 8];
      }
      #pragma unroll
      for (int tn = 0; tn < 4; ++tn) {
        const int row = wn * 64 + tn * 16 + wr;
        const int slot = (ks * 4 + wq) ^ (row & 7);
        bfr[tn] = *(const bf16x8*)&Bbuf[cur][row * 64 + slot * 8];
      }
      __builtin_amdgcn_s_setprio(1);
      #pragma unroll
      for (int tn = 0; tn < 4; ++tn)
        acc[tn] = __builtin_amdgcn_mfma_f32_16x16x32_bf16(af, bfr[tn], acc[tn], 0, 0, 0);
      __builtin_amdgcn_s_setprio(0);
    }
    // pack + write next A tile (sampling threads)
    if (n < 35 && samp) {
      VMWAIT(4);  // drain gathers(n+1); B(n+1) stays in flight
      A_WRITE(nb);
    }
    if (n < 35) {
      LGKM0;
      __builtin_amdgcn_s_barrier();
    }
  }
#undef GATHER_ISSUE
#undef B_ISSUE
#undef A_WRITE

  // ---- epilogue 1: y write [b][s][o]; D layout col=lane&15, row=(lane>>4)*4+r ----
  float* yb = y + ((size_t)(b * 4096 + h * 64 + wh * 32)) * 256;
  #pragma unroll
  for (int tn = 0; tn < 4; ++tn) {
    const int o = wn * 64 + tn * 16 + wr;
    #pragma unroll
    for (int r2 = 0; r2 < 4; ++r2) {
      const int ww = wm * 16 + wq * 4 + r2;
      yb[ww * 256 + o] = acc[tn][r2];
    }
  }
  // ---- epilogue 2: fused GN partial stats ----
  #pragma unroll
  for (int tn = 0; tn < 4; ++tn) {
    float sum = 0.f, ss = 0.f;
    #pragma unroll
    for (int r2 = 0; r2 < 4; ++r2) {
      const float v = acc[tn][r2];
      sum += v;
      ss += v * v;
    }
    sum += __shfl_xor(sum, 16, 64);
    ss += __shfl_xor(ss, 16, 64);
    sum += __shfl_xor(sum, 32, 64);
    ss += __shfl_xor(ss, 32, 64);
    #pragma unroll
    for (int d = 1; d < 8; d <<= 1) {
      sum += __shfl_xor(sum, d, 64);
      ss += __shfl_xor(ss, d, 64);
    }
    if (wq == 0 && (wr & 7) == 0) {
      const int gi = wn * 8 + tn * 2 + (wr >> 3);
      atomicAdd(&stats[(b * 32 + gi) * 2], sum);
      atomicAdd(&stats[(b * 32 + gi) * 2 + 1], ss);
    }
  }
}

// ---------------- GN apply + ReLU, transpose [b][s][o] -> [b][o][s] ----------------
__global__ __launch_bounds__(256) void k_apply(const float* __restrict__ y,
                                               const float* __restrict__ stats,
                                               const float* __restrict__ gamma,
                                               const float* __restrict__ beta,
                                               float* __restrict__ out) {
  __shared__ float tile[64][65];
  __shared__ float sm[8], sr[8], sg[64], sb[64];
  const int bid = blockIdx.x;                    // 1024
  const int lb = ((bid & 7) << 7) | (bid >> 3);  // XCD-contiguous: same b region as k_gemm
  const int b = lb >> 8;
  const int st = (lb >> 2) & 63;
  const int ot = lb & 3;
  const int t = threadIdx.x;
  if (t < 8) {
    const int g = ot * 8 + t;
    const float s1 = stats[(b * 32 + g) * 2];
    const float s2 = stats[(b * 32 + g) * 2 + 1];
    const float mean = s1 * (1.f / 32768.f);
    const float var = s2 * (1.f / 32768.f) - mean * mean;
    sm[t] = mean;
    sr[t] = rsqrtf(var + 1e-5f);
  }
  if (t < 64) {
    sg[t] = gamma[ot * 64 + t];
    sb[t] = beta[ot * 64 + t];
  }
  const float* yb = y + ((size_t)(b * 4096 + st * 64)) * 256 + ot * 64;
  #pragma unroll
  for (int i = 0; i < 16; ++i) {
    const int idx = t + 256 * i;
    const int s_l = idx >> 6, o_l = idx & 63;
    tile[s_l][o_l] = yb[(size_t)s_l * 256 + o_l];
  }
  __syncthreads();
  float* ob = out + ((size_t)(b * 256 + ot * 64)) * 4096 + st * 64;
  #pragma unroll
  for (int i = 0; i < 16; ++i) {
    const int idx = t + 256 * i;
    const int o_l = idx >> 6, s_l = idx & 63;
    const int g = o_l >> 3;
    float v = (tile[s_l][o_l] - sm[g]) * sr[g] * sg[o_l] + sb[o_l];
    v = v > 0.f ? v : 0.f;
    ob[(size_t)o_l * 4096 + s_l] = v;
  }
}

extern "C" void kernel_launch(void* const* d_in, const int* in_sizes, int n_in,
                              void* d_out, int out_size, void* d_ws, size_t ws_size,
                              hipStream_t stream) {
  const float* x = (const float*)d_in[0];       // (4,256,64,64)
  const float* off = (const float*)d_in[1];     // (4,18,64,64)
  const float* w = (const float*)d_in[2];       // (256,256,3,3)
  const float* gamma = (const float*)d_in[3];   // (256)
  const float* beta = (const float*)d_in[4];    // (256)
  float* out = (float*)d_out;

  char* ws = (char*)d_ws;
  float* y = (float*)(ws);                        // 16,777,216 B  [b][s][o] f32
  ushort_t* xt = (ushort_t*)(ws + 16777216);      //  8,388,608 B  [b][h][w][c] bf16
  ushort_t* wb = (ushort_t*)(ws + 25165824);      //  1,179,648 B  [k][o][c] bf16
  float* stats = (float*)(ws + 26345472);         //      1,024 B  [b][g]{sum,ss}

  hipMemsetAsync(stats, 0, 1024, stream);
  k_prep_w<<<256, 256, 0, stream>>>(w, wb);
  k_prep_x<<<1024, 256, 0, stream>>>(x, xt);
  k_gemm<<<512, 512, 0, stream>>>(off, xt, wb, y, stats);
  k_apply<<<1024, 256, 0, stream>>>(y, stats, gamma, beta, out);
}

// Round 7
// 87.327 us; speedup vs baseline: 1.2935x; 1.2935x over previous
//
#include <hip/hip_runtime.h>

typedef unsigned short ushort_t;
typedef __bf16 bf16x8 __attribute__((ext_vector_type(8)));
typedef float f32x4 __attribute__((ext_vector_type(4)));
typedef void __attribute__((address_space(1))) gvoid_t;
typedef void __attribute__((address_space(3))) lvoid_t;

__device__ __forceinline__ float bflo(unsigned u) { return __builtin_bit_cast(float, u << 16); }
__device__ __forceinline__ float bfhi(unsigned u) { return __builtin_bit_cast(float, u & 0xffff0000u); }
__device__ __forceinline__ unsigned f2bf_bits(float f) {
  unsigned u = __builtin_bit_cast(unsigned, f);
  return (u + 0x7fffu + ((u >> 16) & 1u)) >> 16;
}
__device__ __forceinline__ ushort_t f2bf(float f) { return (ushort_t)f2bf_bits(f); }

#define VMWAIT(N) asm volatile("s_waitcnt vmcnt(" #N ")" ::: "memory")
#define LGKM0 asm volatile("s_waitcnt lgkmcnt(0)" ::: "memory")

// ---------------- prep: weight (o,c,k) f32 -> wb[k][o][c] bf16 ----------------
__global__ __launch_bounds__(256) void k_prep_w(const float* __restrict__ w,
                                                ushort_t* __restrict__ wb) {
  const int idx = blockIdx.x * 256 + threadIdx.x;  // (o,c) pair, 65536 total
  const float* src = w + (size_t)idx * 9;
  #pragma unroll
  for (int k = 0; k < 9; ++k)
    wb[(k << 16) + idx] = f2bf(src[k]);
}

// ---------------- prep: x (b,c,h,w) f32 -> xt[b][h][w][c] bf16 ----------------
__global__ __launch_bounds__(256) void k_prep_x(const float* __restrict__ x,
                                                ushort_t* __restrict__ xt) {
  __shared__ ushort_t tile[64][68];
  const int bid = blockIdx.x;             // 4b * 4ct * 64pt = 1024
  const int b = bid >> 8;
  const int ct = (bid >> 6) & 3;
  const int pt = bid & 63;
  const int t = threadIdx.x;
  const float* xb = x + ((size_t)(b * 256 + ct * 64)) * 4096 + pt * 64;
  #pragma unroll
  for (int i = 0; i < 16; ++i) {
    const int idx = t + 256 * i;
    const int c_l = idx >> 6, p_l = idx & 63;
    tile[c_l][p_l] = f2bf(xb[(size_t)c_l * 4096 + p_l]);
  }
  __syncthreads();
  ushort_t* xo = xt + ((size_t)(b * 4096 + pt * 64)) * 256 + ct * 64;
  #pragma unroll
  for (int i = 0; i < 16; ++i) {
    const int idx = t + 256 * i;
    const int p_l = idx >> 6, c_l = idx & 63;
    xo[(size_t)p_l * 256 + c_l] = tile[c_l][p_l];
  }
}

// bilinear meta for one (h, w, tap) — weights and gather base offsets (in ushorts)
struct SMeta {
  float w00, w01, w10, w11;
  int i00, i01, i10, i11;
};
__device__ __forceinline__ SMeta meta_for(int h, int gw, int k, float oy, float ox) {
  SMeta m;
  const float py = (float)(h - 1 + k / 3) + oy;
  const float px = (float)(gw - 1 + k % 3) + ox;
  const float fy = floorf(py), fx = floorf(px);
  const float ly = py - fy, lx = px - fx;
  const int iy0 = (int)fy, ix0 = (int)fx;
  const float vy0 = (iy0 >= 0 && iy0 < 64) ? 1.f : 0.f;
  const float vy1 = (iy0 >= -1 && iy0 < 63) ? 1.f : 0.f;
  const float vx0 = (ix0 >= 0 && ix0 < 64) ? 1.f : 0.f;
  const float vx1 = (ix0 >= -1 && ix0 < 63) ? 1.f : 0.f;
  m.w00 = (1.f - ly) * (1.f - lx) * vy0 * vx0;
  m.w01 = (1.f - ly) * lx * vy0 * vx1;
  m.w10 = ly * (1.f - lx) * vy1 * vx0;
  m.w11 = ly * lx * vy1 * vx1;
  const int cy0 = min(max(iy0, 0), 63), cy1 = min(max(iy0 + 1, 0), 63);
  const int cx0 = min(max(ix0, 0), 63), cx1 = min(max(ix0 + 1, 0), 63);
  m.i00 = (cy0 * 64 + cx0) * 256;
  m.i01 = (cy0 * 64 + cx1) * 256;
  m.i10 = (cy1 * 64 + cx0) * 256;
  m.i11 = (cy1 * 64 + cx1) * 256;
  return m;
}

__device__ __forceinline__ unsigned lerp_pack(unsigned a, unsigned b, unsigned c, unsigned d,
                                              float w00, float w01, float w10, float w11) {
  float lo = w00 * bflo(a) + w01 * bflo(b) + w10 * bflo(c) + w11 * bflo(d);
  float hi = w00 * bfhi(a) + w01 * bfhi(b) + w10 * bfhi(c) + w11 * bfhi(d);
  return f2bf_bits(lo) | (f2bf_bits(hi) << 16);
}

// ---------------- fused deform-sample + GEMM + GN partial stats ----------------
// block = one output row (b,h): BM=64, BN=256, 8 waves (512 thr). grid=256.
// 36 chunks (tap n>>2, channels ((n&3)<<6)..+64).
// Pipeline, all at distance 2: gathers(n+2) into reg-set[(n)&1], B(n+2) into
// Bbuf[(n+2)%3] issued at period n; ONE upfront counted vmcnt per period
// (retires B(n)+gathers(n+1), both a full period old -> free); then ds_read+
// MFMA(n) + pack A(n+1) + ds_write form an asm-free region the compiler
// interleaves across VALU/LDS/MFMA pipes. Single s_barrier per period.
// XCD swizzle: lb=(bid&7)*32+bid/8 -> each XCD works one batch (L2-resident).
__global__ __launch_bounds__(512) void k_gemm(const float* __restrict__ off,
                                              const ushort_t* __restrict__ xt,
                                              const ushort_t* __restrict__ wb,
                                              float* __restrict__ y,
                                              float* __restrict__ stats) {
  __shared__ __attribute__((aligned(16))) ushort_t Abuf[2][64 * 64];   // 16KB
  __shared__ __attribute__((aligned(16))) ushort_t Bbuf[3][256 * 64];  // 96KB

  const int bid = blockIdx.x;                    // 256
  const int lb = ((bid & 7) << 5) | (bid >> 3);  // XCD-contiguous logical id
  const int b = lb >> 6;
  const int h = lb & 63;
  const int t = threadIdx.x;  // 0..511
  const int wave = t >> 6;
  const int lane = t & 63;
  const int wq = lane >> 4;
  const int wr = lane & 15;
  const int wm = wave >> 2;  // M half
  const int wn = wave & 3;   // N quarter

  const int s_w = t >> 3;  // sampling: w column (0..63)
  const int c8 = t & 7;    // sampling: 8-channel slice (0..7)

  const f32x4 zero = {0.f, 0.f, 0.f, 0.f};
  f32x4 acc[2][4];
  #pragma unroll
  for (int i = 0; i < 2; ++i)
    #pragma unroll
    for (int j = 0; j < 4; ++j) acc[i][j] = zero;

  const ushort_t* xtb = xt + (size_t)b * 4096 * 256;

  // hoist all 18 offset values into registers
  float oy[9], ox[9];
  {
    const float* offb = off + (size_t)b * 18 * 4096 + h * 64 + s_w;
    #pragma unroll
    for (int k = 0; k < 9; ++k) {
      oy[k] = offb[(2 * k) * 4096];
      ox[k] = offb[(2 * k + 1) * 4096];
    }
  }

  // double-buffered gather registers + meta (statically indexed: loop fully unrolled)
  uint4 q00s[2], q01s[2], q10s[2], q11s[2];
  SMeta ms[2];

#define GATHER_ISSUE(TAP, C0, SET)                              \
  {                                                             \
    ms[SET] = meta_for(h, s_w, (TAP), oy[(TAP)], ox[(TAP)]);    \
    const int cc = (C0) + c8 * 8;                               \
    q00s[SET] = *(const uint4*)(xtb + ms[SET].i00 + cc);        \
    q01s[SET] = *(const uint4*)(xtb + ms[SET].i01 + cc);        \
    q10s[SET] = *(const uint4*)(xtb + ms[SET].i10 + cc);        \
    q11s[SET] = *(const uint4*)(xtb + ms[SET].i11 + cc);        \
  }

#define B_ISSUE(TAP, C0, BUF)                                                                \
  {                                                                                          \
    _Pragma("unroll") for (int i_ = 0; i_ < 4; ++i_) {                                       \
      const int idx_ = i_ * 512 + t;                                                         \
      const int row_ = idx_ >> 3, slot_ = idx_ & 7;                                          \
      const ushort_t* g_ = wb + ((TAP) << 16) + row_ * 256 + (C0) + ((slot_ ^ (row_ & 7)) << 3); \
      __builtin_amdgcn_global_load_lds((gvoid_t*)g_,                                         \
                                       (lvoid_t*)((char*)&Bbuf[(BUF)][0] + idx_ * 16), 16,   \
                                       0, 0);                                                \
    }                                                                                        \
  }

#define A_WRITE(SET, BUF)                                                         \
  {                                                                               \
    uint4 r;                                                                      \
    r.x = lerp_pack(q00s[SET].x, q01s[SET].x, q10s[SET].x, q11s[SET].x,           \
                    ms[SET].w00, ms[SET].w01, ms[SET].w10, ms[SET].w11);          \
    r.y = lerp_pack(q00s[SET].y, q01s[SET].y, q10s[SET].y, q11s[SET].y,           \
                    ms[SET].w00, ms[SET].w01, ms[SET].w10, ms[SET].w11);          \
    r.z = lerp_pack(q00s[SET].z, q01s[SET].z, q10s[SET].z, q11s[SET].z,           \
                    ms[SET].w00, ms[SET].w01, ms[SET].w10, ms[SET].w11);          \
    r.w = lerp_pack(q00s[SET].w, q01s[SET].w, q10s[SET].w, q11s[SET].w,           \
                    ms[SET].w00, ms[SET].w01, ms[SET].w10, ms[SET].w11);          \
    *(uint4*)&Abuf[(BUF)][s_w * 64 + ((c8 ^ (s_w & 7)) << 3)] = r;                \
  }

  // ---- prologue: issue g(0), B(0), g(1), B(1); pack A(0) ----
  {
    GATHER_ISSUE(0, 0, 0);    // g(0) -> set 0
    B_ISSUE(0, 0, 0);         // B(0) -> buf 0
    GATHER_ISSUE(0, 64, 1);   // g(1): tap 0, c0=64 -> set 1
    B_ISSUE(0, 64, 1);        // B(1) -> buf 1
    VMWAIT(12);               // retire g(0); B(0), g(1), B(1) stay in flight
    A_WRITE(0, 0);
    LGKM0;
    __builtin_amdgcn_s_barrier();
  }

  // ---- main loop: 36 periods, fully unrolled ----
  #pragma unroll
  for (int n = 0; n < 36; ++n) {
    const int curA = n & 1;
    const int nbA = curA ^ 1;
    const int curB = n % 3;
    // 1. single upfront wait: retire B(n) + gathers(n+1) (issued >= 1 period ago)
    if (n == 35) {
      VMWAIT(0);
    } else {
      VMWAIT(4);  // leaves only B(n+1) in flight
    }
    // 2. issue distance-2 prefetches: g(n+2) -> set[n&1], B(n+2) -> buf[(n+2)%3]
    if (n <= 33) {
      GATHER_ISSUE((n + 2) >> 2, ((n + 2) & 3) << 6, curA);
      B_ISSUE((n + 2) >> 2, ((n + 2) & 3) << 6, (n + 2) % 3);
    }
    // 3. asm-free region: MFMA(n) + pack A(n+1) — compiler interleaves pipes
    #pragma unroll
    for (int ks = 0; ks < 2; ++ks) {
      bf16x8 af[2], bfr[4];
      #pragma unroll
      for (int tm = 0; tm < 2; ++tm) {
        const int row = wm * 32 + tm * 16 + wr;
        const int slot = (ks * 4 + wq) ^ (row & 7);
        af[tm] = *(const bf16x8*)&Abuf[curA][row * 64 + slot * 8];
      }
      #pragma unroll
      for (int tn = 0; tn < 4; ++tn) {
        const int row = wn * 64 + tn * 16 + wr;
        const int slot = (ks * 4 + wq) ^ (row & 7);
        bfr[tn] = *(const bf16x8*)&Bbuf[curB][row * 64 + slot * 8];
      }
      #pragma unroll
      for (int tm = 0; tm < 2; ++tm)
        #pragma unroll
        for (int tn = 0; tn < 4; ++tn)
          acc[tm][tn] =
              __builtin_amdgcn_mfma_f32_16x16x32_bf16(af[tm], bfr[tn], acc[tm][tn], 0, 0, 0);
    }
    if (n < 35) {
      A_WRITE(nbA, nbA);  // pack chunk n+1 from set[(n+1)&1] into Abuf[(n+1)&1]
      LGKM0;
      __builtin_amdgcn_s_barrier();
    }
  }
#undef GATHER_ISSUE
#undef B_ISSUE
#undef A_WRITE

  // ---- epilogue 1: y write [b][s][o]; D layout col=lane&15, row=(lane>>4)*4+r ----
  float* yb = y + ((size_t)(b * 4096 + h * 64)) * 256;
  #pragma unroll
  for (int tm = 0; tm < 2; ++tm) {
    #pragma unroll
    for (int tn = 0; tn < 4; ++tn) {
      const int o = wn * 64 + tn * 16 + wr;
      #pragma unroll
      for (int r2 = 0; r2 < 4; ++r2) {
        const int ww = wm * 32 + tm * 16 + wq * 4 + r2;
        yb[ww * 256 + o] = acc[tm][tn][r2];
      }
    }
  }
  // ---- epilogue 2: fused GN partial stats ----
  #pragma unroll
  for (int tn = 0; tn < 4; ++tn) {
    float sum = 0.f, ss = 0.f;
    #pragma unroll
    for (int tm = 0; tm < 2; ++tm)
      #pragma unroll
      for (int r2 = 0; r2 < 4; ++r2) {
        const float v = acc[tm][tn][r2];
        sum += v;
        ss += v * v;
      }
    sum += __shfl_xor(sum, 16, 64);
    ss += __shfl_xor(ss, 16, 64);
    sum += __shfl_xor(sum, 32, 64);
    ss += __shfl_xor(ss, 32, 64);
    #pragma unroll
    for (int d = 1; d < 8; d <<= 1) {
      sum += __shfl_xor(sum, d, 64);
      ss += __shfl_xor(ss, d, 64);
    }
    if (wq == 0 && (wr & 7) == 0) {
      const int gi = wn * 8 + tn * 2 + (wr >> 3);
      atomicAdd(&stats[(b * 32 + gi) * 2], sum);
      atomicAdd(&stats[(b * 32 + gi) * 2 + 1], ss);
    }
  }
}

// ---------------- GN apply + ReLU, transpose [b][s][o] -> [b][o][s] ----------------
__global__ __launch_bounds__(256) void k_apply(const float* __restrict__ y,
                                               const float* __restrict__ stats,
                                               const float* __restrict__ gamma,
                                               const float* __restrict__ beta,
                                               float* __restrict__ out) {
  __shared__ float tile[64][65];
  __shared__ float sm[8], sr[8], sg[64], sb[64];
  const int bid = blockIdx.x;                    // 1024
  const int lb = ((bid & 7) << 7) | (bid >> 3);  // XCD-contiguous: same b region as k_gemm
  const int b = lb >> 8;
  const int st = (lb >> 2) & 63;
  const int ot = lb & 3;
  const int t = threadIdx.x;
  if (t < 8) {
    const int g = ot * 8 + t;
    const float s1 = stats[(b * 32 + g) * 2];
    const float s2 = stats[(b * 32 + g) * 2 + 1];
    const float mean = s1 * (1.f / 32768.f);
    const float var = s2 * (1.f / 32768.f) - mean * mean;
    sm[t] = mean;
    sr[t] = rsqrtf(var + 1e-5f);
  }
  if (t < 64) {
    sg[t] = gamma[ot * 64 + t];
    sb[t] = beta[ot * 64 + t];
  }
  const float* yb = y + ((size_t)(b * 4096 + st * 64)) * 256 + ot * 64;
  #pragma unroll
  for (int i = 0; i < 16; ++i) {
    const int idx = t + 256 * i;
    const int s_l = idx >> 6, o_l = idx & 63;
    tile[s_l][o_l] = yb[(size_t)s_l * 256 + o_l];
  }
  __syncthreads();
  float* ob = out + ((size_t)(b * 256 + ot * 64)) * 4096 + st * 64;
  #pragma unroll
  for (int i = 0; i < 16; ++i) {
    const int idx = t + 256 * i;
    const int o_l = idx >> 6, s_l = idx & 63;
    const int g = o_l >> 3;
    float v = (tile[s_l][o_l] - sm[g]) * sr[g] * sg[o_l] + sb[o_l];
    v = v > 0.f ? v : 0.f;
    ob[(size_t)o_l * 4096 + s_l] = v;
  }
}

extern "C" void kernel_launch(void* const* d_in, const int* in_sizes, int n_in,
                              void* d_out, int out_size, void* d_ws, size_t ws_size,
                              hipStream_t stream) {
  const float* x = (const float*)d_in[0];       // (4,256,64,64)
  const float* off = (const float*)d_in[1];     // (4,18,64,64)
  const float* w = (const float*)d_in[2];       // (256,256,3,3)
  const float* gamma = (const float*)d_in[3];   // (256)
  const float* beta = (const float*)d_in[4];    // (256)
  float* out = (float*)d_out;

  char* ws = (char*)d_ws;
  float* y = (float*)(ws);                        // 16,777,216 B  [b][s][o] f32
  ushort_t* xt = (ushort_t*)(ws + 16777216);      //  8,388,608 B  [b][h][w][c] bf16
  ushort_t* wb = (ushort_t*)(ws + 25165824);      //  1,179,648 B  [k][o][c] bf16
  float* stats = (float*)(ws + 26345472);         //      1,024 B  [b][g]{sum,ss}

  hipMemsetAsync(stats, 0, 1024, stream);
  k_prep_w<<<256, 256, 0, stream>>>(w, wb);
  k_prep_x<<<1024, 256, 0, stream>>>(x, xt);
  k_gemm<<<256, 512, 0, stream>>>(off, xt, wb, y, stats);
  k_apply<<<1024, 256, 0, stream>>>(y, stats, gamma, beta, out);
}

// Round 9
// 83.744 us; speedup vs baseline: 1.3488x; 1.0428x over previous
//
#include <hip/hip_runtime.h>

typedef unsigned short ushort_t;
typedef __bf16 bf16x8 __attribute__((ext_vector_type(8)));
typedef float f32x4 __attribute__((ext_vector_type(4)));
typedef void __attribute__((address_space(1))) gvoid_t;
typedef void __attribute__((address_space(3))) lvoid_t;

__device__ __forceinline__ float bflo(unsigned u) { return __builtin_bit_cast(float, u << 16); }
__device__ __forceinline__ float bfhi(unsigned u) { return __builtin_bit_cast(float, u & 0xffff0000u); }
__device__ __forceinline__ unsigned f2bf_bits(float f) {
  unsigned u = __builtin_bit_cast(unsigned, f);
  return (u + 0x7fffu + ((u >> 16) & 1u)) >> 16;
}
__device__ __forceinline__ ushort_t f2bf(float f) { return (ushort_t)f2bf_bits(f); }

#define VMWAIT(N) asm volatile("s_waitcnt vmcnt(" #N ")" ::: "memory")
#define LGKM0 asm volatile("s_waitcnt lgkmcnt(0)" ::: "memory")

// ---------------- prep: weight (o,c,k) f32 -> wb[k][o][c] bf16 ----------------
__global__ __launch_bounds__(256) void k_prep_w(const float* __restrict__ w,
                                                ushort_t* __restrict__ wb) {
  const int idx = blockIdx.x * 256 + threadIdx.x;  // (o,c) pair, 65536 total
  const float* src = w + (size_t)idx * 9;
  #pragma unroll
  for (int k = 0; k < 9; ++k)
    wb[(k << 16) + idx] = f2bf(src[k]);
}

// ---------------- prep: x (b,c,h,w) f32 -> xt[b][h][w][c] bf16 ----------------
__global__ __launch_bounds__(256) void k_prep_x(const float* __restrict__ x,
                                                ushort_t* __restrict__ xt) {
  __shared__ ushort_t tile[64][68];
  const int bid = blockIdx.x;             // 4b * 4ct * 64pt = 1024
  const int b = bid >> 8;
  const int ct = (bid >> 6) & 3;
  const int pt = bid & 63;
  const int t = threadIdx.x;
  const float* xb = x + ((size_t)(b * 256 + ct * 64)) * 4096 + pt * 64;
  #pragma unroll
  for (int i = 0; i < 16; ++i) {
    const int idx = t + 256 * i;
    const int c_l = idx >> 6, p_l = idx & 63;
    tile[c_l][p_l] = f2bf(xb[(size_t)c_l * 4096 + p_l]);
  }
  __syncthreads();
  ushort_t* xo = xt + ((size_t)(b * 4096 + pt * 64)) * 256 + ct * 64;
  #pragma unroll
  for (int i = 0; i < 16; ++i) {
    const int idx = t + 256 * i;
    const int p_l = idx >> 6, c_l = idx & 63;
    xo[(size_t)p_l * 256 + c_l] = tile[c_l][p_l];
  }
}

// bilinear meta for one (h, w, tap)
struct SMeta {
  float w00, w01, w10, w11;
  int i00, i01, i10, i11;
};
__device__ __forceinline__ SMeta meta_for(int h, int gw, int k, float oy, float ox) {
  SMeta m;
  const float py = (float)(h - 1 + k / 3) + oy;
  const float px = (float)(gw - 1 + k % 3) + ox;
  const float fy = floorf(py), fx = floorf(px);
  const float ly = py - fy, lx = px - fx;
  const int iy0 = (int)fy, ix0 = (int)fx;
  const float vy0 = (iy0 >= 0 && iy0 < 64) ? 1.f : 0.f;
  const float vy1 = (iy0 >= -1 && iy0 < 63) ? 1.f : 0.f;
  const float vx0 = (ix0 >= 0 && ix0 < 64) ? 1.f : 0.f;
  const float vx1 = (ix0 >= -1 && ix0 < 63) ? 1.f : 0.f;
  m.w00 = (1.f - ly) * (1.f - lx) * vy0 * vx0;
  m.w01 = (1.f - ly) * lx * vy0 * vx1;
  m.w10 = ly * (1.f - lx) * vy1 * vx0;
  m.w11 = ly * lx * vy1 * vx1;
  const int cy0 = min(max(iy0, 0), 63), cy1 = min(max(iy0 + 1, 0), 63);
  const int cx0 = min(max(ix0, 0), 63), cx1 = min(max(ix0 + 1, 0), 63);
  m.i00 = (cy0 * 64 + cx0) * 256;
  m.i01 = (cy0 * 64 + cx1) * 256;
  m.i10 = (cy1 * 64 + cx0) * 256;
  m.i11 = (cy1 * 64 + cx1) * 256;
  return m;
}

__device__ __forceinline__ unsigned lerp_pack(unsigned a, unsigned b, unsigned c, unsigned d,
                                              float w00, float w01, float w10, float w11) {
  float lo = w00 * bflo(a) + w01 * bflo(b) + w10 * bflo(c) + w11 * bflo(d);
  float hi = w00 * bfhi(a) + w01 * bfhi(b) + w10 * bfhi(c) + w11 * bfhi(d);
  return f2bf_bits(lo) | (f2bf_bits(hi) << 16);
}

// ---------------- fused deform-sample + GEMM + GN partial stats ----------------
// block = one output row (b,h): BM=64, BN=256, 8 waves (512 thr). grid=256.
// 18 periods of BK=128: period p = tap p>>1, channel-half p&1 (2 chunks of 64).
// Fixed per-period cost (barrier skew + phase serialization, ~2800cyc measured
// R7) amortized over 2x work; total VALU/loads/MFMA unchanged; meta halved.
// Robust schedule (R8 lesson): ONE manual vmcnt per period, wait-to-<=8 right
// after issuing exactly 8 B-loads -> in-order vmcnt retirement guarantees all
// older ops (incl. compiler spills) retired, only the 8 newest stay in flight.
// B(p) is waited BEFORE the end-of-(p-1) barrier (stage->wait->barrier->read)
// so the barrier publishes it to all waves. Gather loads are plain reg loads:
// the compiler inserts their exact waits.
// XCD swizzle: lb=(bid&7)*32+bid/8 -> each XCD works one batch (L2-resident).
__global__ __launch_bounds__(512) void k_gemm(const float* __restrict__ off,
                                              const ushort_t* __restrict__ xt,
                                              const ushort_t* __restrict__ wb,
                                              float* __restrict__ y,
                                              float* __restrict__ stats) {
  __shared__ __attribute__((aligned(16))) ushort_t Abuf[2][2][64 * 64];   // [pbuf][chunk] 32KB
  __shared__ __attribute__((aligned(16))) ushort_t Bbuf[2][2][256 * 64];  // [pbuf][chunk] 128KB

  const int bid = blockIdx.x;                    // 256
  const int lb = ((bid & 7) << 5) | (bid >> 3);  // XCD-contiguous logical id
  const int b = lb >> 6;
  const int h = lb & 63;
  const int t = threadIdx.x;  // 0..511
  const int wave = t >> 6;
  const int lane = t & 63;
  const int wq = lane >> 4;
  const int wr = lane & 15;
  const int wm = wave >> 2;  // M half
  const int wn = wave & 3;   // N quarter

  const int s_w = t >> 3;  // sampling: w column (0..63)
  const int c8 = t & 7;    // sampling: 8-channel slice (0..7)

  const f32x4 zero = {0.f, 0.f, 0.f, 0.f};
  f32x4 acc[2][4];
  #pragma unroll
  for (int i = 0; i < 2; ++i)
    #pragma unroll
    for (int j = 0; j < 4; ++j) acc[i][j] = zero;

  const ushort_t* xtb = xt + (size_t)b * 4096 * 256;

  // hoist all 18 offset values into registers
  float oy[9], ox[9];
  {
    const float* offb = off + (size_t)b * 18 * 4096 + h * 64 + s_w;
    #pragma unroll
    for (int k = 0; k < 9; ++k) {
      oy[k] = offb[(2 * k) * 4096];
      ox[k] = offb[(2 * k + 1) * 4096];
    }
  }

  // single gather state: meta + 2 chunk-slices of 4 corners (scalar regs, no arrays)
  SMeta mg;
  uint4 qa00, qa01, qa10, qa11;  // chunk 0 of the period (cols C0..C0+63)
  uint4 qb00, qb01, qb10, qb11;  // chunk 1 (cols C0+64..C0+127)

  // 8 plain reg loads for period covering tap TAP, base col C0 = (p&1)*128
#define GATHER_ISSUE(TAP, C0)                             \
  {                                                       \
    mg = meta_for(h, s_w, (TAP), oy[(TAP)], ox[(TAP)]);   \
    const int cc = (C0) + c8 * 8;                         \
    qa00 = *(const uint4*)(xtb + mg.i00 + cc);            \
    qa01 = *(const uint4*)(xtb + mg.i01 + cc);            \
    qa10 = *(const uint4*)(xtb + mg.i10 + cc);            \
    qa11 = *(const uint4*)(xtb + mg.i11 + cc);            \
    qb00 = *(const uint4*)(xtb + mg.i00 + cc + 64);       \
    qb01 = *(const uint4*)(xtb + mg.i01 + cc + 64);       \
    qb10 = *(const uint4*)(xtb + mg.i10 + cc + 64);       \
    qb11 = *(const uint4*)(xtb + mg.i11 + cc + 64);       \
  }

  // 8 global_load_lds (2 chunks x 4) into Bbuf[PB][0..1]
#define B_ISSUE(TAP, C0, PB)                                                                   \
  {                                                                                            \
    _Pragma("unroll") for (int ch_ = 0; ch_ < 2; ++ch_) {                                      \
      _Pragma("unroll") for (int i_ = 0; i_ < 4; ++i_) {                                       \
        const int idx_ = i_ * 512 + t;                                                         \
        const int row_ = idx_ >> 3, slot_ = idx_ & 7;                                          \
        const ushort_t* g_ =                                                                   \
            wb + ((TAP) << 16) + row_ * 256 + (C0) + ch_ * 64 + ((slot_ ^ (row_ & 7)) << 3);   \
        __builtin_amdgcn_global_load_lds((gvoid_t*)g_,                                         \
                                         (lvoid_t*)((char*)&Bbuf[(PB)][ch_][0] + idx_ * 16),   \
                                         16, 0, 0);                                            \
      }                                                                                        \
    }                                                                                          \
  }

  // pack both chunk-slices into Abuf[PB][0..1] (compiler waits the gather regs)
#define A_WRITE(PB)                                                                  \
  {                                                                                  \
    uint4 r;                                                                         \
    r.x = lerp_pack(qa00.x, qa01.x, qa10.x, qa11.x, mg.w00, mg.w01, mg.w10, mg.w11); \
    r.y = lerp_pack(qa00.y, qa01.y, qa10.y, qa11.y, mg.w00, mg.w01, mg.w10, mg.w11); \
    r.z = lerp_pack(qa00.z, qa01.z, qa10.z, qa11.z, mg.w00, mg.w01, mg.w10, mg.w11); \
    r.w = lerp_pack(qa00.w, qa01.w, qa10.w, qa11.w, mg.w00, mg.w01, mg.w10, mg.w11); \
    *(uint4*)&Abuf[(PB)][0][s_w * 64 + ((c8 ^ (s_w & 7)) << 3)] = r;                 \
    r.x = lerp_pack(qb00.x, qb01.x, qb10.x, qb11.x, mg.w00, mg.w01, mg.w10, mg.w11); \
    r.y = lerp_pack(qb00.y, qb01.y, qb10.y, qb11.y, mg.w00, mg.w01, mg.w10, mg.w11); \
    r.z = lerp_pack(qb00.z, qb01.z, qb10.z, qb11.z, mg.w00, mg.w01, mg.w10, mg.w11); \
    r.w = lerp_pack(qb00.w, qb01.w, qb10.w, qb11.w, mg.w00, mg.w01, mg.w10, mg.w11); \
    *(uint4*)&Abuf[(PB)][1][s_w * 64 + ((c8 ^ (s_w & 7)) << 3)] = r;                 \
  }

  // ---- prologue: stage period 0, prefetch gathers for period 1, publish ----
  {
    GATHER_ISSUE(0, 0);   // g(0): tap 0, cols 0..127
    B_ISSUE(0, 0, 0);     // B(0) -> pbuf 0
    A_WRITE(0);           // compiler waits g(0); B(0) stays in flight
    GATHER_ISSUE(0, 128); // g(1): tap 0, cols 128..255
    VMWAIT(8);            // in-order retire: everything older than g(1) done (incl B(0))
    LGKM0;
    __builtin_amdgcn_s_barrier();  // publish A(0), B(0)
  }

  // ---- main loop: 18 periods (period p: tap p>>1, C0 = (p&1)*128) ----
  #pragma unroll
  for (int p = 0; p < 18; ++p) {
    const int pb = p & 1;
    const int nb = pb ^ 1;
    // 1. issue B(p+1) (8 async loads) — overlaps with this period's MFMA
    if (p < 17) {
      const int tap1 = (p + 1) >> 1;
      const int c01 = ((p + 1) & 1) << 7;
      B_ISSUE(tap1, c01, nb);
    }
    // 2. MFMA period p: 4 K-steps of 32 over the 2 chunk sub-tiles
    #pragma unroll
    for (int ks = 0; ks < 4; ++ks) {
      const int ch = ks >> 1;
      const int kk = ks & 1;
      bf16x8 af[2], bfr[4];
      #pragma unroll
      for (int tm = 0; tm < 2; ++tm) {
        const int row = wm * 32 + tm * 16 + wr;
        const int slot = (kk * 4 + wq) ^ (row & 7);
        af[tm] = *(const bf16x8*)&Abuf[pb][ch][row * 64 + slot * 8];
      }
      #pragma unroll
      for (int tn = 0; tn < 4; ++tn) {
        const int row = wn * 64 + tn * 16 + wr;
        const int slot = (kk * 4 + wq) ^ (row & 7);
        bfr[tn] = *(const bf16x8*)&Bbuf[pb][ch][row * 64 + slot * 8];
      }
      #pragma unroll
      for (int tm = 0; tm < 2; ++tm)
        #pragma unroll
        for (int tn = 0; tn < 4; ++tn)
          acc[tm][tn] =
              __builtin_amdgcn_mfma_f32_16x16x32_bf16(af[tm], bfr[tn], acc[tm][tn], 0, 0, 0);
    }
    // 3. pack A(p+1) from gathers issued last period (compiler-managed waits)
    if (p < 17) {
      A_WRITE(nb);
      // 4. issue gathers for period p+2 into the (now free) gather regs
      if (p < 16) {
        const int tap2 = (p + 2) >> 1;
        const int c02 = ((p + 2) & 1) << 7;
        GATHER_ISSUE(tap2, c02);
        VMWAIT(8);  // retire everything older than g(p+2) — incl. B(p+1) -> published
      } else {
        VMWAIT(0);  // p==16: retire B(17)
      }
      LGKM0;
      __builtin_amdgcn_s_barrier();  // publish A(p+1), B(p+1)
    }
  }
#undef GATHER_ISSUE
#undef B_ISSUE
#undef A_WRITE

  // ---- epilogue 1: y write [b][s][o]; D layout col=lane&15, row=(lane>>4)*4+r ----
  float* yb = y + ((size_t)(b * 4096 + h * 64)) * 256;
  #pragma unroll
  for (int tm = 0; tm < 2; ++tm) {
    #pragma unroll
    for (int tn = 0; tn < 4; ++tn) {
      const int o = wn * 64 + tn * 16 + wr;
      #pragma unroll
      for (int r2 = 0; r2 < 4; ++r2) {
        const int ww = wm * 32 + tm * 16 + wq * 4 + r2;
        yb[ww * 256 + o] = acc[tm][tn][r2];
      }
    }
  }
  // ---- epilogue 2: fused GN partial stats ----
  #pragma unroll
  for (int tn = 0; tn < 4; ++tn) {
    float sum = 0.f, ss = 0.f;
    #pragma unroll
    for (int tm = 0; tm < 2; ++tm)
      #pragma unroll
      for (int r2 = 0; r2 < 4; ++r2) {
        const float v = acc[tm][tn][r2];
        sum += v;
        ss += v * v;
      }
    sum += __shfl_xor(sum, 16, 64);
    ss += __shfl_xor(ss, 16, 64);
    sum += __shfl_xor(sum, 32, 64);
    ss += __shfl_xor(ss, 32, 64);
    #pragma unroll
    for (int d = 1; d < 8; d <<= 1) {
      sum += __shfl_xor(sum, d, 64);
      ss += __shfl_xor(ss, d, 64);
    }
    if (wq == 0 && (wr & 7) == 0) {
      const int gi = wn * 8 + tn * 2 + (wr >> 3);
      atomicAdd(&stats[(b * 32 + gi) * 2], sum);
      atomicAdd(&stats[(b * 32 + gi) * 2 + 1], ss);
    }
  }
}

// ---------------- GN apply + ReLU, transpose [b][s][o] -> [b][o][s] ----------------
__global__ __launch_bounds__(256) void k_apply(const float* __restrict__ y,
                                               const float* __restrict__ stats,
                                               const float* __restrict__ gamma,
                                               const float* __restrict__ beta,
                                               float* __restrict__ out) {
  __shared__ float tile[64][65];
  __shared__ float sm[8], sr[8], sg[64], sb[64];
  const int bid = blockIdx.x;                    // 1024
  const int lb = ((bid & 7) << 7) | (bid >> 3);  // XCD-contiguous: same b region as k_gemm
  const int b = lb >> 8;
  const int st = (lb >> 2) & 63;
  const int ot = lb & 3;
  const int t = threadIdx.x;
  if (t < 8) {
    const int g = ot * 8 + t;
    const float s1 = stats[(b * 32 + g) * 2];
    const float s2 = stats[(b * 32 + g) * 2 + 1];
    const float mean = s1 * (1.f / 32768.f);
    const float var = s2 * (1.f / 32768.f) - mean * mean;
    sm[t] = mean;
    sr[t] = rsqrtf(var + 1e-5f);
  }
  if (t < 64) {
    sg[t] = gamma[ot * 64 + t];
    sb[t] = beta[ot * 64 + t];
  }
  const float* yb = y + ((size_t)(b * 4096 + st * 64)) * 256 + ot * 64;
  #pragma unroll
  for (int i = 0; i < 16; ++i) {
    const int idx = t + 256 * i;
    const int s_l = idx >> 6, o_l = idx & 63;
    tile[s_l][o_l] = yb[(size_t)s_l * 256 + o_l];
  }
  __syncthreads();
  float* ob = out + ((size_t)(b * 256 + ot * 64)) * 4096 + st * 64;
  #pragma unroll
  for (int i = 0; i < 16; ++i) {
    const int idx = t + 256 * i;
    const int o_l = idx >> 6, s_l = idx & 63;
    const int g = o_l >> 3;
    float v = (tile[s_l][o_l] - sm[g]) * sr[g] * sg[o_l] + sb[o_l];
    v = v > 0.f ? v : 0.f;
    ob[(size_t)o_l * 4096 + s_l] = v;
  }
}

extern "C" void kernel_launch(void* const* d_in, const int* in_sizes, int n_in,
                              void* d_out, int out_size, void* d_ws, size_t ws_size,
                              hipStream_t stream) {
  const float* x = (const float*)d_in[0];       // (4,256,64,64)
  const float* off = (const float*)d_in[1];     // (4,18,64,64)
  const float* w = (const float*)d_in[2];       // (256,256,3,3)
  const float* gamma = (const float*)d_in[3];   // (256)
  const float* beta = (const float*)d_in[4];    // (256)
  float* out = (float*)d_out;

  char* ws = (char*)d_ws;
  float* y = (float*)(ws);                        // 16,777,216 B  [b][s][o] f32
  ushort_t* xt = (ushort_t*)(ws + 16777216);      //  8,388,608 B  [b][h][w][c] bf16
  ushort_t* wb = (ushort_t*)(ws + 25165824);      //  1,179,648 B  [k][o][c] bf16
  float* stats = (float*)(ws + 26345472);         //      1,024 B  [b][g]{sum,ss}

  hipMemsetAsync(stats, 0, 1024, stream);
  k_prep_w<<<256, 256, 0, stream>>>(w, wb);
  k_prep_x<<<1024, 256, 0, stream>>>(x, xt);
  k_gemm<<<256, 512, 0, stream>>>(off, xt, wb, y, stats);
  k_apply<<<1024, 256, 0, stream>>>(y, stats, gamma, beta, out);
}